// Round 1
// baseline (193.369 us; speedup 1.0000x reference)
//
#include <hip/hip_runtime.h>
#include <math.h>

// Problem constants
#define BATCH 2
#define NTOK  2048
#define FIN   256
#define HEADS 8
#define FOUT  32
#define BH    (BATCH*HEADS)    // 16
#define NCOL  (HEADS*FOUT)     // 256
#define ROWS  (BATCH*NTOK)     // 4096

// ---------------------------------------------------------------------------
// Workspace layout (float offsets)
// ---------------------------------------------------------------------------
// Wh   [4096][256]          @ 0          (1,048,576)
// e1   [16][2048]           @ 1,048,576  (32,768)
// e2   [16][2048]           @ 1,081,344  (32,768)
// skey [16][2048]           @ 1,114,112  (32,768)   sorted-descending e2
// sidx [16][2048] (int)     @ 1,146,880  (32,768)   original j of sorted pos
// w1s  [16][2048]           @ 1,179,648  (32,768)   exp(skey)
// w2s  [16][2048]           @ 1,212,416  (32,768)   exp(0.01*skey)
// S1   [16][2049]           @ 1,245,184  (32,784)   excl prefix of w1s (+total)
// P2   [16][2049]           @ 1,277,968  (32,784)   excl prefix of w2s (+total)
// V1   [16][2049][32]       @ 1,310,752  (1,049,088) excl prefix of w1*Wh
// P2V  [16][2049][32]       @ 2,359,840  (1,049,088) excl prefix of w2*Wh
// total 3,408,928 floats = 13.6 MB
static const size_t OFF_E1   = 1048576;
static const size_t OFF_E2   = OFF_E1 + 32768;
static const size_t OFF_SKEY = OFF_E2 + 32768;
static const size_t OFF_SIDX = OFF_SKEY + 32768;
static const size_t OFF_W1S  = OFF_SIDX + 32768;
static const size_t OFF_W2S  = OFF_W1S + 32768;
static const size_t OFF_S1   = OFF_W2S + 32768;
static const size_t OFF_P2   = OFF_S1 + 32784;
static const size_t OFF_V1   = OFF_P2 + 32784;
static const size_t OFF_P2V  = OFF_V1 + 16u*2049u*32u;

// ---------------------------------------------------------------------------
// K1: Wh = h @ W   (4096x256 @ 256x256, fp32)
// grid (256,4), block 256: block = 16 rows x 64 cols; thread = 1 row x float4
// ---------------------------------------------------------------------------
__global__ __launch_bounds__(256) void k_gemm(const float* __restrict__ h,
                                              const float* __restrict__ W,
                                              float* __restrict__ Wh) {
    __shared__ float As[16 * 260];  // +4 pad breaks bank aliasing on row stride
    const int tid  = threadIdx.x;
    const int row0 = blockIdx.x * 16;
    const int col0 = blockIdx.y * 64;

    // stage 16x256 A tile (coalesced float4 global reads, scalar LDS writes)
    const float4* hg = (const float4*)(h + (size_t)row0 * FIN);
    #pragma unroll
    for (int q = 0; q < 4; ++q) {
        int l = q * 256 + tid;          // float4 index 0..1023
        float4 v = hg[l];
        int r  = l >> 6;                // 64 float4 per row
        int c  = (l & 63) * 4;
        As[r * 260 + c + 0] = v.x;
        As[r * 260 + c + 1] = v.y;
        As[r * 260 + c + 2] = v.z;
        As[r * 260 + c + 3] = v.w;
    }
    __syncthreads();

    const int row = tid >> 4;
    const int cg  = tid & 15;
    const float4* W4 = (const float4*)W;   // [256][64] float4
    const int wcol = (col0 >> 2) + cg;
    float4 acc = make_float4(0.f, 0.f, 0.f, 0.f);
    #pragma unroll 8
    for (int k = 0; k < FIN; ++k) {
        float a  = As[row * 260 + k];
        float4 w = W4[k * 64 + wcol];
        acc.x += a * w.x; acc.y += a * w.y; acc.z += a * w.z; acc.w += a * w.w;
    }
    *(float4*)(Wh + (size_t)(row0 + row) * NCOL + col0 + cg * 4) = acc;
}

// ---------------------------------------------------------------------------
// K2: e1[bh][n] = dot(Wh[b,n,h,:], a1), e2 likewise with a2
// grid 128, block 256: one thread per (b,n,h)
// ---------------------------------------------------------------------------
__global__ __launch_bounds__(256) void k_e12(const float* __restrict__ Wh,
                                             const float* __restrict__ a,
                                             float* __restrict__ e1,
                                             float* __restrict__ e2) {
    __shared__ float av[64];
    const int tid = threadIdx.x;
    if (tid < 64) av[tid] = a[tid];
    __syncthreads();

    const int g     = blockIdx.x * 256 + tid;   // 0..32767
    const int n_lin = g >> 3;                   // Wh row
    const int hh    = g & 7;
    const float4* p = (const float4*)(Wh + (size_t)n_lin * NCOL + hh * FOUT);
    float s1 = 0.f, s2 = 0.f;
    #pragma unroll
    for (int q = 0; q < 8; ++q) {
        float4 v = p[q];
        s1 += v.x * av[q*4+0] + v.y * av[q*4+1] + v.z * av[q*4+2] + v.w * av[q*4+3];
        s2 += v.x * av[32+q*4+0] + v.y * av[32+q*4+1] + v.z * av[32+q*4+2] + v.w * av[32+q*4+3];
    }
    const int b  = n_lin >> 11;
    const int n  = n_lin & (NTOK - 1);
    const int bh = b * HEADS + hh;
    e1[bh * NTOK + n] = s1;
    e2[bh * NTOK + n] = s2;
}

// ---------------------------------------------------------------------------
// K3: exact descending rank of e2 within each (b,h) row; scatter key+idx.
// rank = #{jj: e2[jj] > e2[j]} + #{jj < j: e2[jj] == e2[j]}  (exact permutation)
// grid (16 bh, 8 jtile), block 256
// ---------------------------------------------------------------------------
__global__ __launch_bounds__(256) void k_rank(const float* __restrict__ e2g,
                                              float* __restrict__ skey,
                                              int* __restrict__ sidx) {
    __shared__ float e2l[NTOK];
    const int tid = threadIdx.x;
    const int bh  = blockIdx.x;
    const int jt  = blockIdx.y;
    #pragma unroll
    for (int q = 0; q < 8; ++q)
        e2l[q * 256 + tid] = e2g[bh * NTOK + q * 256 + tid];
    __syncthreads();

    const int j    = jt * 256 + tid;
    const float my = e2l[j];
    int rank = 0;
    const float4* e4 = (const float4*)e2l;
    for (int q4 = 0; q4 < NTOK / 4; ++q4) {
        float4 v = e4[q4];
        int base = q4 * 4;
        rank += (v.x > my) || ((v.x == my) && (base + 0 < j));
        rank += (v.y > my) || ((v.y == my) && (base + 1 < j));
        rank += (v.z > my) || ((v.z == my) && (base + 2 < j));
        rank += (v.w > my) || ((v.w == my) && (base + 3 < j));
    }
    skey[bh * NTOK + rank] = my;
    sidx[bh * NTOK + rank] = j;
}

// ---------------------------------------------------------------------------
// K4: w1s = exp(skey), w2s = exp(0.01*skey); exclusive scalar prefix sums
// S1, P2 (length 2049, [2048] = total). grid 16, block 1024.
// ---------------------------------------------------------------------------
__global__ __launch_bounds__(1024) void k_prep(const float* __restrict__ skey,
                                               float* __restrict__ w1s,
                                               float* __restrict__ w2s,
                                               float* __restrict__ S1,
                                               float* __restrict__ P2) {
    __shared__ float w1l[NTOK];
    __shared__ float w2l[NTOK];
    __shared__ float cs1[64];
    __shared__ float cs2[64];
    const int t  = threadIdx.x;
    const int bh = blockIdx.x;

    for (int q = 0; q < 2; ++q) {
        int j = q * 1024 + t;
        float kk = skey[bh * NTOK + j];
        float v1 = expf(kk);
        float v2 = expf(0.01f * kk);
        w1s[bh * NTOK + j] = v1;
        w2s[bh * NTOK + j] = v2;
        w1l[j] = v1;
        w2l[j] = v2;
    }
    __syncthreads();
    if (t < 64) {
        float s1 = 0.f, s2 = 0.f;
        for (int r = 0; r < 32; ++r) { s1 += w1l[t * 32 + r]; s2 += w2l[t * 32 + r]; }
        cs1[t] = s1; cs2[t] = s2;
    }
    __syncthreads();
    if (t == 0) {
        float r1 = 0.f, r2 = 0.f;
        for (int c = 0; c < 64; ++c) {
            float v1 = cs1[c], v2 = cs2[c];
            cs1[c] = r1; cs2[c] = r2;
            r1 += v1; r2 += v2;
        }
        S1[bh * 2049 + 2048] = r1;   // totals
        P2[bh * 2049 + 2048] = r2;
    }
    __syncthreads();
    for (int q = 0; q < 2; ++q) {
        int k = q * 1024 + t;           // 0..2047: exclusive prefix at k
        int c = k >> 5, r = k & 31;
        float s1 = cs1[c], s2 = cs2[c];
        for (int u = 0; u < r; ++u) { s1 += w1l[c * 32 + u]; s2 += w2l[c * 32 + u]; }
        S1[bh * 2049 + k] = s1;
        P2[bh * 2049 + k] = s2;
    }
}

// ---------------------------------------------------------------------------
// K5: vector prefix scans of w*Wh (gathered by sorted index), 4 f-components
// per block, Hillis-Steele in LDS. grid (8 fg, 16 bh, 2 z), block 1024.
// z=0: w1s -> V1 ; z=1: w2s -> P2V.  Writes exclusive form: dst[k]=incl[k-1].
// ---------------------------------------------------------------------------
__global__ __launch_bounds__(1024) void k_vscan(const float* __restrict__ Wh,
                                                const int* __restrict__ sidx,
                                                const float* __restrict__ w1s,
                                                const float* __restrict__ w2s,
                                                float* __restrict__ V1,
                                                float* __restrict__ P2V) {
    __shared__ float4 bufA[NTOK];
    __shared__ float4 bufB[NTOK];
    const int t  = threadIdx.x;
    const int fg = blockIdx.x;
    const int bh = blockIdx.y;
    const int z  = blockIdx.z;
    const int b  = bh >> 3;
    const int hh = bh & 7;
    const float* wsrc = z ? w2s : w1s;
    float* dst = z ? P2V : V1;

    for (int q = 0; q < 2; ++q) {
        int j = q * 1024 + t;
        int sj = sidx[bh * NTOK + j];
        float w = wsrc[bh * NTOK + j];
        float4 v = *(const float4*)(Wh + (size_t)(b * NTOK + sj) * NCOL + hh * FOUT + fg * 4);
        float4 p;
        p.x = w * v.x; p.y = w * v.y; p.z = w * v.z; p.w = w * v.w;
        bufA[j] = p;
    }
    __syncthreads();

    float4* src = bufA;
    float4* dd  = bufB;
    for (int off = 1; off < NTOK; off <<= 1) {
        for (int q = 0; q < 2; ++q) {
            int j = q * 1024 + t;
            float4 v = src[j];
            if (j >= off) {
                float4 u = src[j - off];
                v.x += u.x; v.y += u.y; v.z += u.z; v.w += u.w;
            }
            dd[j] = v;
        }
        __syncthreads();
        float4* tmp = src; src = dd; dd = tmp;
    }
    // inclusive result in src; store exclusive at k = j+1
    for (int q = 0; q < 2; ++q) {
        int j = q * 1024 + t;
        *(float4*)(dst + ((size_t)bh * 2049 + (j + 1)) * 32 + fg * 4) = src[j];
    }
    if (t == 0) {
        float4 z4 = make_float4(0.f, 0.f, 0.f, 0.f);
        *(float4*)(dst + ((size_t)bh * 2049 + 0) * 32 + fg * 4) = z4;
    }
}

// ---------------------------------------------------------------------------
// K6: per (b,h,i): binary-search k_i, combine prefix sums, write output.
// grid (64 itile, 16 bh), block 256 = 32 i x 8 fg
// ---------------------------------------------------------------------------
__global__ __launch_bounds__(256) void k_out(const float* __restrict__ skey,
                                             const float* __restrict__ e1g,
                                             const float* __restrict__ S1,
                                             const float* __restrict__ P2,
                                             const float* __restrict__ V1,
                                             const float* __restrict__ P2V,
                                             float* __restrict__ out) {
    __shared__ float keys[NTOK];
    const int tid = threadIdx.x;
    const int it  = blockIdx.x;
    const int bh  = blockIdx.y;
    const int b   = bh >> 3;
    const int hh  = bh & 7;
    #pragma unroll
    for (int q = 0; q < 8; ++q)
        keys[q * 256 + tid] = skey[bh * NTOK + q * 256 + tid];
    __syncthreads();

    const int i  = it * 32 + (tid >> 3);
    const int fg = tid & 7;
    const float e1v = e1g[bh * NTOK + i];
    const float th  = -e1v;
    // count of keys > th (keys descending)
    int lo = 0, hi = NTOK;
    while (lo < hi) {
        int mid = (lo + hi) >> 1;
        if (keys[mid] > th) lo = mid + 1; else hi = mid;
    }
    const int k = lo;
    const float A = expf(e1v);
    const float C = expf(0.01f * e1v);
    const float s1  = S1[bh * 2049 + k];
    const float p2k = P2[bh * 2049 + k];
    const float p2t = P2[bh * 2049 + 2048];
    const float l   = A * s1 + C * (p2t - p2k);
    const float inv = 1.0f / l;
    float4 v1   = *(const float4*)(V1  + ((size_t)bh * 2049 + k)    * 32 + fg * 4);
    float4 p2v  = *(const float4*)(P2V + ((size_t)bh * 2049 + k)    * 32 + fg * 4);
    float4 p2vt = *(const float4*)(P2V + ((size_t)bh * 2049 + 2048) * 32 + fg * 4);
    float4 o;
    o.x = (A * v1.x + C * (p2vt.x - p2v.x)) * inv;
    o.y = (A * v1.y + C * (p2vt.y - p2v.y)) * inv;
    o.z = (A * v1.z + C * (p2vt.z - p2v.z)) * inv;
    o.w = (A * v1.w + C * (p2vt.w - p2v.w)) * inv;
    *(float4*)(out + (size_t)(b * NTOK + i) * NCOL + hh * FOUT + fg * 4) = o;
}

// ---------------------------------------------------------------------------
extern "C" void kernel_launch(void* const* d_in, const int* in_sizes, int n_in,
                              void* d_out, int out_size, void* d_ws, size_t ws_size,
                              hipStream_t stream) {
    const float* h = (const float*)d_in[0];
    // d_in[1] = adj — unused by the reference computation
    const float* W = (const float*)d_in[2];
    const float* a = (const float*)d_in[3];
    float* out = (float*)d_out;
    float* ws  = (float*)d_ws;

    float* Wh   = ws;
    float* e1   = ws + OFF_E1;
    float* e2   = ws + OFF_E2;
    float* skey = ws + OFF_SKEY;
    int*   sidx = (int*)(ws + OFF_SIDX);
    float* w1s  = ws + OFF_W1S;
    float* w2s  = ws + OFF_W2S;
    float* S1   = ws + OFF_S1;
    float* P2   = ws + OFF_P2;
    float* V1   = ws + OFF_V1;
    float* P2V  = ws + OFF_P2V;

    k_gemm <<<dim3(ROWS / 16, NCOL / 64), 256, 0, stream>>>(h, W, Wh);
    k_e12  <<<dim3(ROWS * HEADS / 256),   256, 0, stream>>>(Wh, a, e1, e2);
    k_rank <<<dim3(BH, NTOK / 256),       256, 0, stream>>>(e2, skey, sidx);
    k_prep <<<dim3(BH),                  1024, 0, stream>>>(skey, w1s, w2s, S1, P2);
    k_vscan<<<dim3(8, BH, 2),            1024, 0, stream>>>(Wh, sidx, w1s, w2s, V1, P2V);
    k_out  <<<dim3(NTOK / 32, BH),        256, 0, stream>>>(skey, e1, S1, P2, V1, P2V, out);
}

// Round 2
// 126.520 us; speedup vs baseline: 1.5284x; 1.5284x over previous
//
#include <hip/hip_runtime.h>
#include <math.h>

// Problem constants
#define BATCH 2
#define NTOK  2048
#define FIN   256
#define HEADS 8
#define FOUT  32
#define BH    (BATCH*HEADS)    // 16
#define NCOL  (HEADS*FOUT)     // 256
#define ROWS  (BATCH*NTOK)     // 4096

// ---------------------------------------------------------------------------
// Workspace layout (float offsets) — same as R1; partial ranks alias V1
// (rank8 writes partial -> scatter reads it -> vscan overwrites V1 later;
//  strict stream order makes the aliasing safe).
// ---------------------------------------------------------------------------
static const size_t OFF_E1   = 1048576;                 // e1  [16][2048]
static const size_t OFF_E2   = OFF_E1 + 32768;          // e2  [16][2048]
static const size_t OFF_SKEY = OFF_E2 + 32768;          // skey[16][2048]
static const size_t OFF_SIDX = OFF_SKEY + 32768;        // sidx[16][2048] int
static const size_t OFF_W1S  = OFF_SIDX + 32768;        // w1s [16][2048]
static const size_t OFF_W2S  = OFF_W1S + 32768;         // w2s [16][2048]
static const size_t OFF_S1   = OFF_W2S + 32768;         // S1  [16][2049]
static const size_t OFF_P2   = OFF_S1 + 32784;          // P2  [16][2049]
static const size_t OFF_V1   = OFF_P2 + 32784;          // V1  [16][2049][32]
static const size_t OFF_P2V  = OFF_V1 + 16u*2049u*32u;  // P2V [16][2049][32]
static const size_t OFF_PART = OFF_V1;                  // partial[8][16][2048] int (aliases V1)

// ---------------------------------------------------------------------------
// K1: Wh = h @ W  (4096x256 @ 256x256 fp32). Tile 32 rows x 64 cols, BK=64.
// grid (128,4)=512 blocks (2 blocks/CU), block 256: thread = 2 rows x float4.
// Both operands staged in LDS -> global traffic 128 KB/block (was ~1 MB).
// ---------------------------------------------------------------------------
__global__ __launch_bounds__(256) void k_gemm(const float* __restrict__ h,
                                              const float* __restrict__ W,
                                              float* __restrict__ Wh) {
    __shared__ float As[32 * 68];   // [row][k], row stride 68 (16B-aligned, bank-safe)
    __shared__ float Bs[64 * 68];   // [k][col], k stride 68
    const int tid  = threadIdx.x;
    const int row0 = blockIdx.x * 32;
    const int col0 = blockIdx.y * 64;
    const int tc = tid & 15;        // float4 col 0..15
    const int tr = tid >> 4;        // row pair 0..15
    const int r0 = tr * 2;

    const float4* h4 = (const float4*)h;   // [4096][64]
    const float4* W4 = (const float4*)W;   // [256][64]

    float4 acc0 = make_float4(0.f,0.f,0.f,0.f);
    float4 acc1 = make_float4(0.f,0.f,0.f,0.f);

    for (int kc = 0; kc < FIN; kc += 64) {
        // stage A: 32 rows x 16 float4 (512 f4, 2/thread), coalesced
        #pragma unroll
        for (int q = 0; q < 2; ++q) {
            int idx = q * 256 + tid;
            int r  = idx >> 4;
            int kq = idx & 15;
            float4 v = h4[(size_t)(row0 + r) * 64 + (kc >> 2) + kq];
            *(float4*)&As[r * 68 + kq * 4] = v;
        }
        // stage B: 64 k x 16 float4 (1024 f4, 4/thread), coalesced
        #pragma unroll
        for (int q = 0; q < 4; ++q) {
            int idx = q * 256 + tid;
            int kr = idx >> 4;
            int cf = idx & 15;
            float4 v = W4[(size_t)(kc + kr) * 64 + (col0 >> 2) + cf];
            *(float4*)&Bs[kr * 68 + cf * 4] = v;
        }
        __syncthreads();

        #pragma unroll
        for (int kq = 0; kq < 16; ++kq) {
            float4 af0 = *(const float4*)&As[r0 * 68 + kq * 4];
            float4 af1 = *(const float4*)&As[(r0 + 1) * 68 + kq * 4];
            #pragma unroll
            for (int c = 0; c < 4; ++c) {
                float4 b = *(const float4*)&Bs[(kq * 4 + c) * 68 + tc * 4];
                float a0 = (c == 0) ? af0.x : (c == 1) ? af0.y : (c == 2) ? af0.z : af0.w;
                float a1 = (c == 0) ? af1.x : (c == 1) ? af1.y : (c == 2) ? af1.z : af1.w;
                acc0.x += a0 * b.x; acc0.y += a0 * b.y; acc0.z += a0 * b.z; acc0.w += a0 * b.w;
                acc1.x += a1 * b.x; acc1.y += a1 * b.y; acc1.z += a1 * b.z; acc1.w += a1 * b.w;
            }
        }
        __syncthreads();
    }
    *(float4*)(Wh + (size_t)(row0 + r0)     * NCOL + col0 + tc * 4) = acc0;
    *(float4*)(Wh + (size_t)(row0 + r0 + 1) * NCOL + col0 + tc * 4) = acc1;
}

// ---------------------------------------------------------------------------
// K2: e1[bh][n] = dot(Wh[b,n,h,:], a1), e2 likewise with a2
// ---------------------------------------------------------------------------
__global__ __launch_bounds__(256) void k_e12(const float* __restrict__ Wh,
                                             const float* __restrict__ a,
                                             float* __restrict__ e1,
                                             float* __restrict__ e2) {
    __shared__ float av[64];
    const int tid = threadIdx.x;
    if (tid < 64) av[tid] = a[tid];
    __syncthreads();

    const int g     = blockIdx.x * 256 + tid;   // 0..32767
    const int n_lin = g >> 3;
    const int hh    = g & 7;
    const float4* p = (const float4*)(Wh + (size_t)n_lin * NCOL + hh * FOUT);
    float s1 = 0.f, s2 = 0.f;
    #pragma unroll
    for (int q = 0; q < 8; ++q) {
        float4 v = p[q];
        s1 += v.x * av[q*4+0] + v.y * av[q*4+1] + v.z * av[q*4+2] + v.w * av[q*4+3];
        s2 += v.x * av[32+q*4+0] + v.y * av[32+q*4+1] + v.z * av[32+q*4+2] + v.w * av[32+q*4+3];
    }
    const int b  = n_lin >> 11;
    const int n  = n_lin & (NTOK - 1);
    const int bh = b * HEADS + hh;
    e1[bh * NTOK + n] = s1;
    e2[bh * NTOK + n] = s2;
}

// ---------------------------------------------------------------------------
// K3a: partial descending ranks. grid (16 bh, 8 jtile, 8 ktile), block 256.
// Each block: 256 j's vs one 256-chunk -> partial count. 1024 blocks.
// ---------------------------------------------------------------------------
__global__ __launch_bounds__(256) void k_rank8(const float* __restrict__ e2g,
                                               int* __restrict__ partial) {
    __shared__ float ch[256];
    const int tid = threadIdx.x;
    const int bh  = blockIdx.x;
    const int jt  = blockIdx.y;
    const int kt  = blockIdx.z;
    ch[tid] = e2g[bh * NTOK + kt * 256 + tid];
    __syncthreads();

    const int j    = jt * 256 + tid;
    const float my = e2g[bh * NTOK + j];
    const int base0 = kt * 256;
    int rank = 0;
    const float4* c4 = (const float4*)ch;
    #pragma unroll 8
    for (int q = 0; q < 64; ++q) {
        float4 v = c4[q];
        int bb = base0 + q * 4;
        rank += (v.x > my) || ((v.x == my) && (bb + 0 < j));
        rank += (v.y > my) || ((v.y == my) && (bb + 1 < j));
        rank += (v.z > my) || ((v.z == my) && (bb + 2 < j));
        rank += (v.w > my) || ((v.w == my) && (bb + 3 < j));
    }
    partial[(kt * BH + bh) * NTOK + j] = rank;
}

// ---------------------------------------------------------------------------
// K3b: sum 8 partials -> rank; scatter key/idx and exp weights.
// grid (16,8), block 256.
// ---------------------------------------------------------------------------
__global__ __launch_bounds__(256) void k_scatter(const float* __restrict__ e2g,
                                                 const int* __restrict__ partial,
                                                 float* __restrict__ skey,
                                                 int* __restrict__ sidx,
                                                 float* __restrict__ w1s,
                                                 float* __restrict__ w2s) {
    const int tid = threadIdx.x;
    const int bh  = blockIdx.x;
    const int jt  = blockIdx.y;
    const int j   = jt * 256 + tid;
    int rank = 0;
    #pragma unroll
    for (int kt = 0; kt < 8; ++kt)
        rank += partial[(kt * BH + bh) * NTOK + j];
    const float my = e2g[bh * NTOK + j];
    skey[bh * NTOK + rank] = my;
    sidx[bh * NTOK + rank] = j;
    w1s[bh * NTOK + rank]  = expf(my);
    w2s[bh * NTOK + rank]  = expf(0.01f * my);
}

// ---------------------------------------------------------------------------
// K4: work-efficient scans. grid (9 fg, 16 bh, 2 z), block 1024.
// fg<8 : float4 scan of w*Wh[.., fg*4..]  -> V1 (z=0) / P2V (z=1)
// fg==8: scalar scan of w                 -> S1 (z=0) / P2  (z=1)
// Thread t owns j=2t,2t+1; wave shfl scan; 16-wave combine. LDS = 0.5 KB.
// Writes exclusive form dst[k]=incl[k-1], dst[0]=0, dst[2048]=total.
// ---------------------------------------------------------------------------
__global__ __launch_bounds__(1024) void k_vscan(const float* __restrict__ Wh,
                                                const int* __restrict__ sidx,
                                                const float* __restrict__ w1s,
                                                const float* __restrict__ w2s,
                                                float* __restrict__ V1,
                                                float* __restrict__ P2V,
                                                float* __restrict__ S1,
                                                float* __restrict__ P2) {
    __shared__ float4 wtot[16];
    __shared__ float4 woff[16];
    const int t    = threadIdx.x;
    const int lane = t & 63;
    const int wv   = t >> 6;
    const int fg   = blockIdx.x;
    const int bh   = blockIdx.y;
    const int z    = blockIdx.z;
    const int b    = bh >> 3;
    const int hh   = bh & 7;
    const float* wsrc = z ? w2s : w1s;

    const int j0 = 2 * t;
    float4 v0, v1;
    if (fg < 8) {
        int sj0 = sidx[bh * NTOK + j0];
        int sj1 = sidx[bh * NTOK + j0 + 1];
        float w0 = wsrc[bh * NTOK + j0];
        float w1 = wsrc[bh * NTOK + j0 + 1];
        float4 g0 = *(const float4*)(Wh + (size_t)(b * NTOK + sj0) * NCOL + hh * FOUT + fg * 4);
        float4 g1 = *(const float4*)(Wh + (size_t)(b * NTOK + sj1) * NCOL + hh * FOUT + fg * 4);
        v0 = make_float4(w0 * g0.x, w0 * g0.y, w0 * g0.z, w0 * g0.w);
        v1 = make_float4(w1 * g1.x, w1 * g1.y, w1 * g1.z, w1 * g1.w);
    } else {
        v0 = make_float4(wsrc[bh * NTOK + j0],     0.f, 0.f, 0.f);
        v1 = make_float4(wsrc[bh * NTOK + j0 + 1], 0.f, 0.f, 0.f);
    }

    // thread-local pair sum, then inclusive wave scan
    float4 s = make_float4(v0.x + v1.x, v0.y + v1.y, v0.z + v1.z, v0.w + v1.w);
    #pragma unroll
    for (int d = 1; d < 64; d <<= 1) {
        float ux = __shfl_up(s.x, (unsigned)d, 64);
        float uy = __shfl_up(s.y, (unsigned)d, 64);
        float uz = __shfl_up(s.z, (unsigned)d, 64);
        float uw = __shfl_up(s.w, (unsigned)d, 64);
        if (lane >= d) { s.x += ux; s.y += uy; s.z += uz; s.w += uw; }
    }
    // exclusive-within-wave
    float4 pair = make_float4(v0.x + v1.x, v0.y + v1.y, v0.z + v1.z, v0.w + v1.w);
    float4 excl = make_float4(s.x - pair.x, s.y - pair.y, s.z - pair.z, s.w - pair.w);
    if (lane == 63) wtot[wv] = s;
    __syncthreads();
    if (t < 16) {
        float4 ws = wtot[t];
        float4 inc = ws;
        #pragma unroll
        for (int d = 1; d < 16; d <<= 1) {
            float ux = __shfl_up(inc.x, (unsigned)d, 16);
            float uy = __shfl_up(inc.y, (unsigned)d, 16);
            float uz = __shfl_up(inc.z, (unsigned)d, 16);
            float uw = __shfl_up(inc.w, (unsigned)d, 16);
            if ((t & 15) >= d) { inc.x += ux; inc.y += uy; inc.z += uz; inc.w += uw; }
        }
        woff[t] = make_float4(inc.x - ws.x, inc.y - ws.y, inc.z - ws.z, inc.w - ws.w);
    }
    __syncthreads();

    float4 base = woff[wv];
    float4 i0 = make_float4(base.x + excl.x + v0.x, base.y + excl.y + v0.y,
                            base.z + excl.z + v0.z, base.w + excl.w + v0.w);
    float4 i1 = make_float4(i0.x + v1.x, i0.y + v1.y, i0.z + v1.z, i0.w + v1.w);

    if (fg < 8) {
        float* dst = z ? P2V : V1;
        *(float4*)(dst + ((size_t)bh * 2049 + (j0 + 1)) * 32 + fg * 4) = i0;
        *(float4*)(dst + ((size_t)bh * 2049 + (j0 + 2)) * 32 + fg * 4) = i1;
        if (t == 0)
            *(float4*)(dst + ((size_t)bh * 2049) * 32 + fg * 4) = make_float4(0.f,0.f,0.f,0.f);
    } else {
        float* dst = z ? P2 : S1;
        dst[bh * 2049 + j0 + 1] = i0.x;
        dst[bh * 2049 + j0 + 2] = i1.x;
        if (t == 0) dst[bh * 2049] = 0.f;
    }
}

// ---------------------------------------------------------------------------
// K5: per (b,h,i): binary-search k_i, combine prefix sums, write output.
// grid (64 itile, 16 bh), block 256 = 32 i x 8 fg
// ---------------------------------------------------------------------------
__global__ __launch_bounds__(256) void k_out(const float* __restrict__ skey,
                                             const float* __restrict__ e1g,
                                             const float* __restrict__ S1,
                                             const float* __restrict__ P2,
                                             const float* __restrict__ V1,
                                             const float* __restrict__ P2V,
                                             float* __restrict__ out) {
    __shared__ float keys[NTOK];
    const int tid = threadIdx.x;
    const int it  = blockIdx.x;
    const int bh  = blockIdx.y;
    const int b   = bh >> 3;
    const int hh  = bh & 7;
    #pragma unroll
    for (int q = 0; q < 8; ++q)
        keys[q * 256 + tid] = skey[bh * NTOK + q * 256 + tid];
    __syncthreads();

    const int i  = it * 32 + (tid >> 3);
    const int fg = tid & 7;
    const float e1v = e1g[bh * NTOK + i];
    const float th  = -e1v;
    int lo = 0, hi = NTOK;
    while (lo < hi) {
        int mid = (lo + hi) >> 1;
        if (keys[mid] > th) lo = mid + 1; else hi = mid;
    }
    const int k = lo;
    const float A = expf(e1v);
    const float C = expf(0.01f * e1v);
    const float s1  = S1[bh * 2049 + k];
    const float p2k = P2[bh * 2049 + k];
    const float p2t = P2[bh * 2049 + 2048];
    const float l   = A * s1 + C * (p2t - p2k);
    const float inv = 1.0f / l;
    float4 v1   = *(const float4*)(V1  + ((size_t)bh * 2049 + k)    * 32 + fg * 4);
    float4 p2v  = *(const float4*)(P2V + ((size_t)bh * 2049 + k)    * 32 + fg * 4);
    float4 p2vt = *(const float4*)(P2V + ((size_t)bh * 2049 + 2048) * 32 + fg * 4);
    float4 o;
    o.x = (A * v1.x + C * (p2vt.x - p2v.x)) * inv;
    o.y = (A * v1.y + C * (p2vt.y - p2v.y)) * inv;
    o.z = (A * v1.z + C * (p2vt.z - p2v.z)) * inv;
    o.w = (A * v1.w + C * (p2vt.w - p2v.w)) * inv;
    *(float4*)(out + (size_t)(b * NTOK + i) * NCOL + hh * FOUT + fg * 4) = o;
}

// ---------------------------------------------------------------------------
extern "C" void kernel_launch(void* const* d_in, const int* in_sizes, int n_in,
                              void* d_out, int out_size, void* d_ws, size_t ws_size,
                              hipStream_t stream) {
    const float* h = (const float*)d_in[0];
    // d_in[1] = adj — unused by the reference computation
    const float* W = (const float*)d_in[2];
    const float* a = (const float*)d_in[3];
    float* out = (float*)d_out;
    float* ws  = (float*)d_ws;

    float* Wh   = ws;
    float* e1   = ws + OFF_E1;
    float* e2   = ws + OFF_E2;
    float* skey = ws + OFF_SKEY;
    int*   sidx = (int*)(ws + OFF_SIDX);
    float* w1s  = ws + OFF_W1S;
    float* w2s  = ws + OFF_W2S;
    float* S1   = ws + OFF_S1;
    float* P2   = ws + OFF_P2;
    float* V1   = ws + OFF_V1;
    float* P2V  = ws + OFF_P2V;
    int*   part = (int*)(ws + OFF_PART);   // aliases V1 (safe: consumed before vscan)

    k_gemm   <<<dim3(ROWS / 32, NCOL / 64), 256, 0, stream>>>(h, W, Wh);
    k_e12    <<<dim3(ROWS * HEADS / 256),   256, 0, stream>>>(Wh, a, e1, e2);
    k_rank8  <<<dim3(BH, 8, 8),             256, 0, stream>>>(e2, part);
    k_scatter<<<dim3(BH, 8),                256, 0, stream>>>(e2, part, skey, sidx, w1s, w2s);
    k_vscan  <<<dim3(9, BH, 2),            1024, 0, stream>>>(Wh, sidx, w1s, w2s, V1, P2V, S1, P2);
    k_out    <<<dim3(NTOK / 32, BH),        256, 0, stream>>>(skey, e1, S1, P2, V1, P2V, out);
}